// Round 1
// baseline (193.994 us; speedup 1.0000x reference)
//
#include <hip/hip_runtime.h>
#include <math.h>

// Cross-entropy: loss = mean_b( logsumexp(x[b,:]) - x[b, t_b] )
// B=8192, V=32000 fp32. HBM-bound: ~1.05 GB read once.

#define LOG2E 1.4426950408889634f
#define LN2   0.6931471805599453f

__global__ __launch_bounds__(256) void ce_row_kernel(const float* __restrict__ x,
                                                     const int* __restrict__ tgt,
                                                     float* __restrict__ row_loss,
                                                     int V) {
    const int row = blockIdx.x;
    const float* xr = x + (size_t)row * (size_t)V;
    const int tid = threadIdx.x;

    // Online logsumexp over this thread's strided slice (float4 vectorized).
    float m = -INFINITY;
    float s = 0.0f;
    const int nvec = V >> 2;                 // 8000 (V % 4 == 0)
    const float4* __restrict__ xv = (const float4*)xr;

    for (int i = tid; i < nvec; i += 256) {
        float4 v = xv[i];
        float vm = fmaxf(fmaxf(v.x, v.y), fmaxf(v.z, v.w));
        float mn = fmaxf(m, vm);
        // rescale old sum, add 4 new terms (exp(a) = exp2(a*log2e) -> v_exp_f32)
        s = s * exp2f((m - mn) * LOG2E)
          + exp2f((v.x - mn) * LOG2E)
          + exp2f((v.y - mn) * LOG2E)
          + exp2f((v.z - mn) * LOG2E)
          + exp2f((v.w - mn) * LOG2E);
        m = mn;
    }

    // Wave (64-lane) butterfly merge of (m, s) pairs.
    #pragma unroll
    for (int off = 1; off < 64; off <<= 1) {
        float om = __shfl_xor(m, off);
        float os = __shfl_xor(s, off);
        float mn = fmaxf(m, om);
        s = s * exp2f((m - mn) * LOG2E) + os * exp2f((om - mn) * LOG2E);
        m = mn;
    }

    // Cross-wave merge (4 waves).
    __shared__ float sm[4], ss[4];
    const int wave = tid >> 6;
    if ((tid & 63) == 0) { sm[wave] = m; ss[wave] = s; }
    __syncthreads();

    if (tid == 0) {
        float M = sm[0], S = ss[0];
        #pragma unroll
        for (int w = 1; w < 4; ++w) {
            float om = sm[w], os = ss[w];
            float mn = fmaxf(M, om);
            S = S * exp2f((M - mn) * LOG2E) + os * exp2f((om - mn) * LOG2E);
            M = mn;
        }
        float lse = M + log2f(S) * LN2;
        int t = tgt[row];
        row_loss[row] = lse - xr[t];
    }
}

// Deterministic single-block reduction of per-row losses -> mean.
__global__ __launch_bounds__(256) void ce_reduce_kernel(const float* __restrict__ row_loss,
                                                        float* __restrict__ out, int B) {
    float acc = 0.0f;
    for (int i = threadIdx.x; i < B; i += 256) acc += row_loss[i];
    #pragma unroll
    for (int off = 1; off < 64; off <<= 1) acc += __shfl_xor(acc, off);
    __shared__ float sa[4];
    if ((threadIdx.x & 63) == 0) sa[threadIdx.x >> 6] = acc;
    __syncthreads();
    if (threadIdx.x == 0) out[0] = (sa[0] + sa[1] + sa[2] + sa[3]) / (float)B;
}

extern "C" void kernel_launch(void* const* d_in, const int* in_sizes, int n_in,
                              void* d_out, int out_size, void* d_ws, size_t ws_size,
                              hipStream_t stream) {
    const float* x = (const float*)d_in[0];
    const int* tgt = (const int*)d_in[1];
    float* out = (float*)d_out;
    float* ws = (float*)d_ws;   // B floats of per-row loss

    const int B = in_sizes[1];                 // 8192
    const int V = in_sizes[0] / B;             // 32000

    ce_row_kernel<<<B, 256, 0, stream>>>(x, tgt, ws, V);
    ce_reduce_kernel<<<1, 256, 0, stream>>>(ws, out, B);
}